// Round 11
// baseline (119.601 us; speedup 1.0000x reference)
//
#include <hip/hip_runtime.h>
#include <cstdint>

#define IN_DIM   128
#define OUT_DIM  256
#define NROWS    32768
#define BM       64            // rows per block
#define NSTEPS   32            // K = 4096 = 32 * 128 (BK=128: 4 i-values/step)
#define STR      65            // bf16x8 row stride (64 + 1 pad)

typedef unsigned short u16;
typedef __attribute__((ext_vector_type(8)))  __bf16 bf16x8;
typedef __attribute__((ext_vector_type(16))) float  f32x16;

// lgkm-only barrier (proven safe v10): drains LDS ops, leaves B loads in
// flight across the barrier.
#define BARRIER_LGKM()                                         \
    do {                                                       \
        asm volatile("s_waitcnt lgkmcnt(0)" ::: "memory");     \
        __builtin_amdgcn_s_barrier();                          \
    } while (0)

// ---------------------------------------------------------------------------
// Prep: repack fouriercoeffs (2,256,128,16) f32 -> Bpack bf16 [K/8][256][8]
// with k = i*32 + t*16 + g  (t: 0=cos, 1=sin; slot g holds harmonic g+1).
// ---------------------------------------------------------------------------
__global__ __launch_bounds__(256) void kan_prep(const float* __restrict__ C,
                                                u16* __restrict__ Bpack) {
    const int o = threadIdx.x;   // 0..255 output channel
    const int i = blockIdx.x;    // 0..127 input dim
    const int t = blockIdx.y;    // 0=cos, 1=sin
    const float* src = C + (((size_t)(t * OUT_DIM + o) * IN_DIM + i) * 16);
    bf16x8 lo = {}, hi = {};
#pragma unroll
    for (int g = 0; g < 8; ++g) {
        lo[g] = (__bf16)src[g];
        hi[g] = (__bf16)src[8 + g];
    }
    const int ko = i * 4 + t * 2;       // k>>3
    bf16x8* dst = (bf16x8*)Bpack;
    dst[(size_t)ko * OUT_DIM + o]       = lo;   // g = 0..7
    dst[(size_t)(ko + 1) * OUT_DIM + o] = hi;   // g = 8..15
}

// ---------------------------------------------------------------------------
// Fused trig + bf16 MFMA GEMM, v11 = v10 + producer/consumer wave split.
//  - 384 threads = 4 consumer waves (wid 0-3: ds_read + MFMA + B loads ONLY)
//    + 2 producer waves (wid 4-5: trig gen ONLY). Consumers' serial stream
//    loses all gen VALU; producers' pure-VALU stream co-schedules with
//    consumer MFMA on the same SIMD (m114). 512 blocks x 6 waves = 3072
//    waves = exactly 3/SIMD, all resident.
//  - Barriers uniform & unconditional (no v4-class conditional sync). Role
//    split is static per wave. dbuf A-LDS / bA-bB B pipeline / epilogue /
//    numerics v10-verbatim. 1/64 + 1/64 traffic ledger intact.
//  - Producers: 128 threads x 2 rows (tr and tr+32) per kt.
// ---------------------------------------------------------------------------
__global__ __launch_bounds__(384, 2) void kan_gemm(const float* __restrict__ x,
                                                   const u16* __restrict__ Bpack,
                                                   const float* __restrict__ bias,
                                                   float* __restrict__ out) {
    __shared__ __align__(16) u16 Asm[2][16 * STR * 8];   // 2 x 16640 B

    const int tid  = threadIdx.x;
    const int lane = tid & 63;
    const int wid  = tid >> 6;       // 0..5
    const bool isProd = (wid >= 4);
    const int wn   = wid & 3;        // consumer col block (64 cols)
    const int la31 = lane & 31;
    const int gh   = lane >> 5;      // 0..1  k-half within a K=16 window
    const int m0   = blockIdx.x * BM;

    // producer task mapping: pid 0..127 -> rows (tr, tr+32), i-sub til
    const int pid = tid - 256;       // valid when isProd
    const int tr  = (pid >> 2) & 31; // 0..31
    const int til = pid & 3;         // 0..3, i = kt*4 + til

    f32x16 vz;
#pragma unroll
    for (int r = 0; r < 16; ++r) vz[r] = 0.f;
    f32x16 acc[2][2] = {{vz, vz}, {vz, vz}};

    const bf16x8* Bv = (const bf16x8*)Bpack;
    bf16x8* Av0 = (bf16x8*)Asm[0];
    bf16x8* Av1 = (bf16x8*)Asm[1];

    const int bcol = wn * 64 + la31;           // + fn*32 per fragment

    // ---- harmonic generator (numerics v10-verbatim): 4 ds_write_b128 ----
    auto gen = [&](bf16x8* Av, float xv, int trL) {
        float s1, c1;
        __sincosf(xv, &s1, &c1);
        const float t2 = 2.f * c1;
        bf16x8 qc0 = {}, qc1 = {}, qs0 = {}, qs1 = {};
        float cp = c1, sp = s1;                    // harmonic 1
        float cc = t2 * c1 - 1.f, sc = t2 * s1;    // harmonic 2
        qc0[0] = (__bf16)cp;  qs0[0] = (__bf16)sp;
        qc0[1] = (__bf16)cc;  qs0[1] = (__bf16)sc;
#pragma unroll
        for (int g = 3; g <= 16; ++g) {            // Chebyshev: 2 FMA each
            const float cn = t2 * cc - cp;
            const float sn = t2 * sc - sp;
            cp = cc; sp = sc; cc = cn; sc = sn;
            const int idx = g - 1;                 // slot = harmonic-1
            if (idx < 8) { qc0[idx] = (__bf16)cc;      qs0[idx] = (__bf16)sc; }
            else         { qc1[idx - 8] = (__bf16)cc;  qs1[idx - 8] = (__bf16)sc; }
        }
        const int kob = til * 4;   // local ko = til*4 + t*2 + (g>>3)
        Av[(kob + 0) * STR + trL] = qc0;
        Av[(kob + 1) * STR + trL] = qc1;
        Av[(kob + 2) * STR + trL] = qs0;
        Av[(kob + 3) * STR + trL] = qs1;
    };

    // producer x pointers (rows tr and tr+32 of this block)
    const float* xP0 = x + (size_t)(m0 + tr) * IN_DIM + til;
    const float* xP1 = xP0 + 32 * IN_DIM;

    // consumer B fragment pipeline: bA kw0-3, bB kw4-7 (static idx only)
    bf16x8 bA[8], bB[8];

    // ---- prologue ----
    float xa = 0.f, xb = 0.f;
    if (isProd) {
        gen(Av0, xP0[0], tr);
        gen(Av0, xP1[0], tr + 32);
        xa = xP0[4];
        xb = xP1[4];
    } else {
#pragma unroll
        for (int j = 0; j < 4; ++j)
#pragma unroll
            for (int fn = 0; fn < 2; ++fn)
                bA[j * 2 + fn] = Bv[(size_t)((j >> 1) * 4 + (j & 1) * 2 + gh) * OUT_DIM
                                    + bcol + fn * 32];
    }
    BARRIER_LGKM();

    for (int kt = 0; kt < NSTEPS; ++kt) {
        bf16x8* Avc = (kt & 1) ? Av1 : Av0;
        bf16x8* Avn = (kt & 1) ? Av0 : Av1;

        if (isProd) {
            // ---- producer: generate next A tile (pure VALU + ds_write) ----
            if (kt + 1 < NSTEPS) {
                gen(Avn, xa, tr);
                gen(Avn, xb, tr + 32);
                const int k2 = ((kt + 2) & (NSTEPS - 1)) * 4;
                xa = xP0[k2];
                xb = xP1[k2];
            }
        } else {
            // ---- consumer: B loads + ds_read + MFMA only ----
            // issue bB: kw4-7 of THIS kt
#pragma unroll
            for (int j = 0; j < 4; ++j)
#pragma unroll
                for (int fn = 0; fn < 2; ++fn)
                    bB[j * 2 + fn] = Bv[(size_t)(kt * 16 + 8 + (j >> 1) * 4 + (j & 1) * 2 + gh)
                                        * OUT_DIM + bcol + fn * 32];

            // MFMA kw0-3 from bA (in flight across the previous barrier)
#pragma unroll
            for (int j = 0; j < 4; ++j) {
                const int koL = (j >> 1) * 4 + (j & 1) * 2 + gh;
                const bf16x8 af0 = Avc[koL * STR + la31];
                const bf16x8 af1 = Avc[koL * STR + 32 + la31];
                acc[0][0] = __builtin_amdgcn_mfma_f32_32x32x16_bf16(af0, bA[j*2+0], acc[0][0], 0, 0, 0);
                acc[0][1] = __builtin_amdgcn_mfma_f32_32x32x16_bf16(af0, bA[j*2+1], acc[0][1], 0, 0, 0);
                acc[1][0] = __builtin_amdgcn_mfma_f32_32x32x16_bf16(af1, bA[j*2+0], acc[1][0], 0, 0, 0);
                acc[1][1] = __builtin_amdgcn_mfma_f32_32x32x16_bf16(af1, bA[j*2+1], acc[1][1], 0, 0, 0);
            }

            // issue bA: kw0-3 of NEXT kt (stays in flight across the barrier)
            {
                const int ktn = (kt + 1) & (NSTEPS - 1);
#pragma unroll
                for (int j = 0; j < 4; ++j)
#pragma unroll
                    for (int fn = 0; fn < 2; ++fn)
                        bA[j * 2 + fn] = Bv[(size_t)(ktn * 16 + (j >> 1) * 4 + (j & 1) * 2 + gh)
                                            * OUT_DIM + bcol + fn * 32];
            }

            // MFMA kw4-7 from bB
#pragma unroll
            for (int j = 0; j < 4; ++j) {
                const int koL = 8 + (j >> 1) * 4 + (j & 1) * 2 + gh;
                const bf16x8 af0 = Avc[koL * STR + la31];
                const bf16x8 af1 = Avc[koL * STR + 32 + la31];
                acc[0][0] = __builtin_amdgcn_mfma_f32_32x32x16_bf16(af0, bB[j*2+0], acc[0][0], 0, 0, 0);
                acc[0][1] = __builtin_amdgcn_mfma_f32_32x32x16_bf16(af0, bB[j*2+1], acc[0][1], 0, 0, 0);
                acc[1][0] = __builtin_amdgcn_mfma_f32_32x32x16_bf16(af1, bB[j*2+0], acc[1][0], 0, 0, 0);
                acc[1][1] = __builtin_amdgcn_mfma_f32_32x32x16_bf16(af1, bB[j*2+1], acc[1][1], 0, 0, 0);
            }
        }
        BARRIER_LGKM();
    }

    if (isProd) return;

    // ---- epilogue (v10 verbatim): col=lane&31, row=(r&3)+8*(r>>2)+4*gh ----
#pragma unroll
    for (int fn = 0; fn < 2; ++fn) {
        const int col = bcol + fn * 32;
        const float bv = bias[col];
#pragma unroll
        for (int fm = 0; fm < 2; ++fm) {
            const int rbase = m0 + fm * 32 + 4 * gh;
#pragma unroll
            for (int r = 0; r < 16; ++r) {
                const int row = rbase + (r & 3) + 8 * (r >> 2);
                out[(size_t)row * OUT_DIM + col] = acc[fm][fn][r] + bv;
            }
        }
    }
}

extern "C" void kernel_launch(void* const* d_in, const int* in_sizes, int n_in,
                              void* d_out, int out_size, void* d_ws, size_t ws_size,
                              hipStream_t stream) {
    const float* x    = (const float*)d_in[0];   // (32768, 128) f32
    const float* fc   = (const float*)d_in[1];   // (2, 256, 128, 16) f32
    const float* bias = (const float*)d_in[2];   // (1, 256) f32
    float* out        = (float*)d_out;           // (32768, 256) f32
    u16* Bpack        = (u16*)d_ws;              // 4096*256*2 B = 2 MB scratch

    kan_prep<<<dim3(IN_DIM, 2), OUT_DIM, 0, stream>>>(fc, Bpack);
    kan_gemm<<<dim3(NROWS / BM), 384, 0, stream>>>(x, Bpack, bias, out);
}

// Round 12
// 95.626 us; speedup vs baseline: 1.2507x; 1.2507x over previous
//
#include <hip/hip_runtime.h>
#include <cstdint>

#define IN_DIM   128
#define OUT_DIM  256
#define NROWS    32768
#define NSTEPS   32            // K = 4096 = 32 * 128 (4 i-values per kt)

typedef unsigned short u16;
typedef __attribute__((ext_vector_type(8)))  __bf16 bf16x8;
typedef __attribute__((ext_vector_type(16))) float  f32x16;
typedef __attribute__((ext_vector_type(4)))  float  f32x4v;

// ---------------------------------------------------------------------------
// Prep: repack fouriercoeffs (2,256,128,16) f32 -> Bpack bf16 [K/8][256][8]
// with k = i*32 + t*16 + g  (t: 0=cos, 1=sin; slot g holds harmonic g+1).
// ---------------------------------------------------------------------------
__global__ __launch_bounds__(256) void kan_prep(const float* __restrict__ C,
                                                u16* __restrict__ Bpack) {
    const int o = threadIdx.x;   // 0..255 output channel
    const int i = blockIdx.x;    // 0..127 input dim
    const int t = blockIdx.y;    // 0=cos, 1=sin
    const float* src = C + (((size_t)(t * OUT_DIM + o) * IN_DIM + i) * 16);
    bf16x8 lo = {}, hi = {};
#pragma unroll
    for (int g = 0; g < 8; ++g) {
        lo[g] = (__bf16)src[g];
        hi[g] = (__bf16)src[8 + g];
    }
    const int ko = i * 4 + t * 2;       // k>>3
    bf16x8* dst = (bf16x8*)Bpack;
    dst[(size_t)ko * OUT_DIM + o]       = lo;   // g = 0..7
    dst[(size_t)(ko + 1) * OUT_DIM + o] = hi;   // g = 8..15
}

// ---------------------------------------------------------------------------
// Fused trig + bf16 MFMA GEMM, v12: A GENERATED DIRECTLY IN REGISTERS.
//  - Key insight: mfma_32x32x16 A-fragment layout (row=lane&31,
//    k=(lane>>5)*8+e) means lane (la31,gh) needs exactly ONE bf16x8 of
//    harmonics {gh*8+1..gh*8+8} of x[row][i] — computable in-lane by the
//    Chebyshev chain. NO A-LDS, NO ds ops, NO barriers anywhere.
//  - 1 wave/block, wave tile 64x128 (fm=2 x fn=4 of 32x32x16). Grid 1024
//    (512 row-groups x 2 col-groups) = 4 waves/CU = 1/SIMD, all resident.
//  - Trig redundancy 4x (2 col-waves x 2 gh-halves): gen VALU ~1200cy/SIMD/kt
//    hides under MFMA-pipe 2067cy. B/FLOP = 1/64 (proven safe rate).
//  - With no barriers the compiler freely software-pipelines B loads across
//    windows/iterations (the thing every barrier variant defeated).
//  - launch_bounds(64,1): VGPR budget up to ~450 (m08), need ~250.
// ---------------------------------------------------------------------------
__global__ __launch_bounds__(64, 1) void kan_gemm(const float* __restrict__ x,
                                                  const u16* __restrict__ Bpack,
                                                  const float* __restrict__ bias,
                                                  float* __restrict__ out) {
    const int lane = threadIdx.x;    // 0..63
    const int la31 = lane & 31;
    const int gh   = lane >> 5;      // 0..1: k-half within each K=16 window
    const int bid  = blockIdx.x;
    const int wn   = bid & 1;        // col group: 128 cols
    const int m0   = (bid >> 1) * 64;

    f32x16 vz;
#pragma unroll
    for (int r = 0; r < 16; ++r) vz[r] = 0.f;
    f32x16 acc[2][4] = {{vz, vz, vz, vz}, {vz, vz, vz, vz}};

    const bf16x8* Bv = (const bf16x8*)Bpack;
    const int bcol = wn * 128 + la31;          // + fn*32 per fragment

    const float* xr0 = x + (size_t)(m0 + la31) * IN_DIM;   // row la31
    const float* xr1 = xr0 + (size_t)32 * IN_DIM;          // row la31+32

    // Chebyshev chain: 16 harmonics of xv; emit this lane's gh-half as the
    // MFMA A-fragments for the cos window (afc) and sin window (afs).
    auto chain = [&](float xv, bf16x8& afc, bf16x8& afs) {
        float s1, c1;
        __sincosf(xv, &s1, &c1);
        const float t2 = 2.f * c1;
        bf16x8 qc0 = {}, qc1 = {}, qs0 = {}, qs1 = {};
        float cp = c1, sp = s1;                    // harmonic 1
        float cc = t2 * c1 - 1.f, sc = t2 * s1;    // harmonic 2
        qc0[0] = (__bf16)cp;  qs0[0] = (__bf16)sp;
        qc0[1] = (__bf16)cc;  qs0[1] = (__bf16)sc;
#pragma unroll
        for (int g = 3; g <= 16; ++g) {            // 2 FMA per harmonic
            const float cn = t2 * cc - cp;
            const float sn = t2 * sc - sp;
            cp = cc; sp = sc; cc = cn; sc = sn;
            const int idx = g - 1;                 // slot = harmonic-1
            if (idx < 8) { qc0[idx] = (__bf16)cc;      qs0[idx] = (__bf16)sc; }
            else         { qc1[idx - 8] = (__bf16)cc;  qs1[idx - 8] = (__bf16)sc; }
        }
        afc = gh ? qc1 : qc0;   // 4 v_cndmask each
        afs = gh ? qs1 : qs0;
    };

    // x double-buffer (4 floats per row per kt, 16B-aligned)
    f32x4v xa = *(const f32x4v*)(xr0);
    f32x4v xb = *(const f32x4v*)(xr1);

    for (int kt = 0; kt < NSTEPS; ++kt) {
        const int ktn = (kt + 1) & (NSTEPS - 1);
        const f32x4v xa_n = *(const f32x4v*)(xr0 + ktn * 4);
        const f32x4v xb_n = *(const f32x4v*)(xr1 + ktn * 4);

#pragma unroll
        for (int i = 0; i < 4; ++i) {
            // B fragments for this i's cos & sin windows.
            // ko = i_glob*4 + t*2 + gh, i_glob = kt*4+i  (matches kan_prep)
            const size_t koc = (size_t)((kt * 4 + i) * 4 + gh);
            bf16x8 bgc[4], bgs[4];
#pragma unroll
            for (int fn = 0; fn < 4; ++fn) {
                bgc[fn] = Bv[koc * OUT_DIM + bcol + fn * 32];
                bgs[fn] = Bv[(koc + 2) * OUT_DIM + bcol + fn * 32];
            }

            // A fragments: harmonic chains for this lane's two rows
            // (~110 VALU inst between B issue and B use: covers L2 latency)
            bf16x8 afc0, afs0, afc1, afs1;
            chain(xa[i], afc0, afs0);
            chain(xb[i], afc1, afs1);

            // cos window (k = i_glob*32 + 0..15)
#pragma unroll
            for (int fn = 0; fn < 4; ++fn) {
                acc[0][fn] = __builtin_amdgcn_mfma_f32_32x32x16_bf16(afc0, bgc[fn], acc[0][fn], 0, 0, 0);
                acc[1][fn] = __builtin_amdgcn_mfma_f32_32x32x16_bf16(afc1, bgc[fn], acc[1][fn], 0, 0, 0);
            }
            // sin window (k = i_glob*32 + 16..31)
#pragma unroll
            for (int fn = 0; fn < 4; ++fn) {
                acc[0][fn] = __builtin_amdgcn_mfma_f32_32x32x16_bf16(afs0, bgs[fn], acc[0][fn], 0, 0, 0);
                acc[1][fn] = __builtin_amdgcn_mfma_f32_32x32x16_bf16(afs1, bgs[fn], acc[1][fn], 0, 0, 0);
            }
        }
        xa = xa_n;
        xb = xb_n;
    }

    // ---- epilogue (v7-verified 32x32 C/D layout):
    //      col = lane&31 (+fn*32), row = (r&3) + 8*(r>>2) + 4*gh (+fm*32)
#pragma unroll
    for (int fn = 0; fn < 4; ++fn) {
        const int col = bcol + fn * 32;
        const float bv = bias[col];
#pragma unroll
        for (int fm = 0; fm < 2; ++fm) {
            const int rbase = m0 + fm * 32 + 4 * gh;
#pragma unroll
            for (int r = 0; r < 16; ++r) {
                const int row = rbase + (r & 3) + 8 * (r >> 2);
                out[(size_t)row * OUT_DIM + col] = acc[fm][fn][r] + bv;
            }
        }
    }
}

extern "C" void kernel_launch(void* const* d_in, const int* in_sizes, int n_in,
                              void* d_out, int out_size, void* d_ws, size_t ws_size,
                              hipStream_t stream) {
    const float* x    = (const float*)d_in[0];   // (32768, 128) f32
    const float* fc   = (const float*)d_in[1];   // (2, 256, 128, 16) f32
    const float* bias = (const float*)d_in[2];   // (1, 256) f32
    float* out        = (float*)d_out;           // (32768, 256) f32
    u16* Bpack        = (u16*)d_ws;              // 4096*256*2 B = 2 MB scratch

    kan_prep<<<dim3(IN_DIM, 2), OUT_DIM, 0, stream>>>(fc, Bpack);
    kan_gemm<<<dim3(NROWS / 64 * 2), 64, 0, stream>>>(x, Bpack, bias, out);
}